// Round 6
// baseline (2965.031 us; speedup 1.0000x reference)
//
#include <hip/hip_runtime.h>
#include <hip/hip_bf16.h>
#include <hip/hip_fp16.h>
#include <math.h>

#define Q_N 4096
#define M_N 65536
#define D_N 1024
#define TOPK 8
#define SEGS 32
#define KPS (M_N / SEGS)       // 2048 keys per segment
#define CANDS (SEGS * TOPK)    // 256 candidates per query
#define NRES 32                // rescored candidates per query

// MFMA tile params
#define BM 128
#define BN 128
#define BK 32
#define NSUB (KPS / BN)        // 16 subtiles per segment
#define NKT (D_N / BK)         // 32 K-steps per subtile
#define NSTEP (NSUB * NKT)     // 512 pipeline steps per segment
#define NSTT (4 * NSTEP)       // 2048 steps: 4 segments per block

typedef short s16x8 __attribute__((ext_vector_type(8)));
typedef float f32x4 __attribute__((ext_vector_type(4)));

__device__ __forceinline__ bool better(float v0, int i0, float v1, int i1) {
  return (v0 > v1) || (v0 == v1 && i0 < i1);
}

__device__ __forceinline__ unsigned short f2bf(float f) {
  union { __hip_bfloat16 h; unsigned short u; } c;
  c.h = __float2bfloat16(f);
  return c.u;
}

// async global->LDS, 16B per lane; lds base wave-uniform, dest linear (lane*16)
__device__ __forceinline__ void gll16(void* lds, const void* g) {
  __builtin_amdgcn_global_load_lds(
      (const __attribute__((address_space(1))) unsigned int*)(uintptr_t)g,
      (__attribute__((address_space(3))) unsigned int*)(uintptr_t)lds, 16, 0, 0);
}

// ---------------- K1: key norms + normalized bf16 conversion ----------------
__global__ __launch_bounds__(256) void knorm_scale_kernel(const float* __restrict__ keys,
                                                          unsigned short* __restrict__ kb,
                                                          float* __restrict__ rnk) {
  int row = blockIdx.x;
  int tid = threadIdx.x;
  float4 v = reinterpret_cast<const float4*>(keys + (size_t)row * D_N)[tid];
  float s = v.x * v.x + v.y * v.y + v.z * v.z + v.w * v.w;
#pragma unroll
  for (int off = 32; off > 0; off >>= 1) s += __shfl_down(s, off);
  __shared__ float part[4];
  __shared__ float rs;
  int lane = tid & 63, wid = tid >> 6;
  if (lane == 0) part[wid] = s;
  __syncthreads();
  if (tid == 0) {
    float t = part[0] + part[1] + part[2] + part[3];
    rs = 1.0f / fmaxf(sqrtf(t), 1e-12f);
  }
  __syncthreads();
  float r = rs;
  ushort4 o;
  o.x = f2bf(v.x * r); o.y = f2bf(v.y * r); o.z = f2bf(v.z * r); o.w = f2bf(v.w * r);
  reinterpret_cast<ushort4*>(kb + (size_t)row * D_N)[tid] = o;
  if (tid == 0) rnk[row] = r;
}

// ---------------- K2: query norms -> fp32 (rescore) + bf16 (MFMA) ----------
__global__ __launch_bounds__(256) void qnorm_dual_kernel(const float* __restrict__ q,
                                                         float* __restrict__ qn,
                                                         unsigned short* __restrict__ qb) {
  int row = blockIdx.x;
  int tid = threadIdx.x;
  float4 v = reinterpret_cast<const float4*>(q + (size_t)row * D_N)[tid];
  float s = v.x * v.x + v.y * v.y + v.z * v.z + v.w * v.w;
#pragma unroll
  for (int off = 32; off > 0; off >>= 1) s += __shfl_down(s, off);
  __shared__ float part[4];
  __shared__ float rs;
  int lane = tid & 63, wid = tid >> 6;
  if (lane == 0) part[wid] = s;
  __syncthreads();
  if (tid == 0) {
    float t = part[0] + part[1] + part[2] + part[3];
    rs = 1.0f / fmaxf(sqrtf(t), 1e-12f);
  }
  __syncthreads();
  float r = rs;
  float4 o;
  o.x = v.x * r; o.y = v.y * r; o.z = v.z * r; o.w = v.w * r;
  reinterpret_cast<float4*>(qn + (size_t)row * D_N)[tid] = o;
  ushort4 ob;
  ob.x = f2bf(o.x); ob.y = f2bf(o.y); ob.z = f2bf(o.z); ob.w = f2bf(o.w);
  reinterpret_cast<ushort4*>(qb + (size_t)row * D_N)[tid] = ob;
}

// ---------------- K3: bf16 MFMA sims + in-register per-segment top-8 --------
// grid = 256 (1 block/CU): block = (xcd = bid&7, qtile = bid>>3). Each block
// sweeps its XCD's 4 segments sequentially in ONE continuous 2048-step
// pipeline -> at any instant an XCD's 32 blocks share ONE 4MB key panel
// (L2-resident; whole kb L3-resident). Swapped-operand MFMA keeps top-8
// fully in registers; candidates dumped at each 512-step segment boundary.
__global__ __launch_bounds__(256) void simsb_kernel(const unsigned short* __restrict__ qb,
                                                    const unsigned short* __restrict__ kb,
                                                    float* __restrict__ cand_val,
                                                    int* __restrict__ cand_idx) {
  __shared__ __align__(16) unsigned short As[2][BM * BK];  // 2 x 8 KB queries
  __shared__ __align__(16) unsigned short Bs[2][BN * BK];  // 2 x 8 KB keys
  __shared__ float mgv[BM * 4 * TOPK];                     // 16 KB merge scratch
  __shared__ int mgi[BM * 4 * TOPK];                       // 16 KB

  const int tid = threadIdx.x;
  const int lane = tid & 63;
  const int wid = tid >> 6;

  const int orig = blockIdx.x;       // 0..255, round-robin over XCDs
  const int xcd = orig & 7;
  const int qtile = orig >> 3;       // 0..31
  const int qbase = qtile * BM;

  // staging geometry: wave wid stages rows [wid*32, wid*32+32) of A and B
  // involutive chunk swizzle on global source; LDS dest linear
  const int srow = (wid << 5) + (lane >> 2);
  const int scol = (((lane & 3) ^ ((lane >> 3) & 3)) << 3);
  const unsigned short* aSeg = qb + (size_t)(qbase + srow) * D_N + scol;
  // key row for step v: xcd*8192 + (v>>5)*128 + srow (contiguous across segs)
  const unsigned short* bSeg = kb + (size_t)((xcd << 13) + srow) * D_N + scol;

  // fragment geometry: fr = row-within-16, g = k-chunk group
  const int fr = lane & 15;
  const int g = lane >> 4;
  const int chunk_phys = g ^ ((fr >> 1) & 3);
  const int bBase = (fr << 5) + (chunk_phys << 3);                  // keys tile
  const int aBase = (((wid << 5) + fr) << 5) + (chunk_phys << 3);   // query tile

  // per-lane running top-8 for 2 queries (q = qbase + wid*32 + n*16 + fr),
  // over this lane's key partition (keys m*16 + g*4 + j) of the current seg
  float lv[2][TOPK];
  int li[2][TOPK];
#pragma unroll
  for (int n = 0; n < 2; ++n)
#pragma unroll
    for (int j = 0; j < TOPK; ++j) { lv[n][j] = -1e30f; li[n][j] = 0x7fffffff; }

  f32x4 acc[8][2];
#pragma unroll
  for (int m = 0; m < 8; ++m)
#pragma unroll
    for (int n = 0; n < 2; ++n) acc[m][n] = (f32x4)0.0f;

  // prologue: stage steps 0,1
#pragma unroll
  for (int p = 0; p < 2; ++p) {
    const unsigned short* aS = aSeg + ((p & 31) << 5);
    const unsigned short* bS = bSeg + (size_t)(p >> 5) * (128 * D_N) + ((p & 31) << 5);
    gll16(As[p] + (wid << 10), aS);
    gll16(As[p] + (wid << 10) + 512, aS + (size_t)16 * D_N);
    gll16(Bs[p] + (wid << 10), bS);
    gll16(Bs[p] + (wid << 10) + 512, bS + (size_t)16 * D_N);
  }

#pragma unroll 1
  for (int v = 0; v < NSTT; ++v) {
    if (v < NSTT - 1) {
      asm volatile("s_waitcnt vmcnt(4)" ::: "memory");
    } else {
      asm volatile("s_waitcnt vmcnt(0)" ::: "memory");
    }
    __builtin_amdgcn_sched_barrier(0);
    __builtin_amdgcn_s_barrier();
    __builtin_amdgcn_sched_barrier(0);

    const unsigned short* Ab = As[v & 1];
    const unsigned short* Bb = Bs[v & 1];
    s16x8 af[8], bq[2];
#pragma unroll
    for (int m = 0; m < 8; ++m) af[m] = *(const s16x8*)(Bb + bBase + (m << 9));
#pragma unroll
    for (int n = 0; n < 2; ++n) bq[n] = *(const s16x8*)(Ab + aBase + (n << 9));
    asm volatile("s_waitcnt lgkmcnt(0)" ::: "memory");
    __builtin_amdgcn_sched_barrier(0);
    __builtin_amdgcn_s_barrier();   // all waves' frag reads done
    __builtin_amdgcn_sched_barrier(0);

    // restage the just-read buffer with step v+2 (stays in flight across barriers)
    if (v + 2 < NSTT) {
      const int v2 = v + 2;
      const unsigned short* aS = aSeg + ((v2 & 31) << 5);
      const unsigned short* bS = bSeg + (size_t)(v2 >> 5) * (128 * D_N) + ((v2 & 31) << 5);
      gll16(As[v & 1] + (wid << 10), aS);
      gll16(As[v & 1] + (wid << 10) + 512, aS + (size_t)16 * D_N);
      gll16(Bs[v & 1] + (wid << 10), bS);
      gll16(Bs[v & 1] + (wid << 10) + 512, bS + (size_t)16 * D_N);
    }

#pragma unroll
    for (int m = 0; m < 8; ++m)
#pragma unroll
      for (int n = 0; n < 2; ++n)
        acc[m][n] = __builtin_amdgcn_mfma_f32_16x16x32_bf16(af[m], bq[n], acc[m][n], 0, 0, 0);

    // subtile boundary: fold acc into per-lane top-8, reset acc (register-only)
    if ((v & (NKT - 1)) == NKT - 1) {
      const int kb0 = (xcd << 13) + ((v >> 5) << 7) + (g << 2);
#pragma unroll
      for (int n = 0; n < 2; ++n)
#pragma unroll
        for (int m = 0; m < 8; ++m)
#pragma unroll
          for (int j = 0; j < 4; ++j) {
            float val = acc[m][n][j];
            acc[m][n][j] = 0.0f;
            int id = kb0 + (m << 4) + j;
            if (better(val, id, lv[n][TOPK - 1], li[n][TOPK - 1])) {
              float cv = val; int ci = id;
#pragma unroll
              for (int p = 0; p < TOPK; ++p) {
                if (better(cv, ci, lv[n][p], li[n][p])) {
                  float tv = lv[n][p]; int ti = li[n][p];
                  lv[n][p] = cv; li[n][p] = ci;
                  cv = tv; ci = ti;
                }
              }
            }
          }
    }

    // segment boundary: dump per-lane lists, merge, write candidates, reset
    if ((v & (NSTEP - 1)) == NSTEP - 1) {
      const int seg = (xcd << 2) + (v >> 9);
      __syncthreads();   // (drains in-flight stages early; harmless)
#pragma unroll
      for (int n = 0; n < 2; ++n) {
        const int ql = (wid << 5) + (n << 4) + fr;
#pragma unroll
        for (int j = 0; j < TOPK; ++j) {
          mgv[((ql << 2) + g) * TOPK + j] = lv[n][j];
          mgi[((ql << 2) + g) * TOPK + j] = li[n][j];
        }
      }
      __syncthreads();
      if (tid < BM) {
        const int rb = tid << 5;   // 4 sorted lists x 8
        int p0 = 0, p1 = 0, p2 = 0, p3 = 0;
        size_t base = (size_t)(qbase + tid) * CANDS + seg * TOPK;
#pragma unroll
        for (int j = 0; j < TOPK; ++j) {
          float v0 = mgv[rb + 0 + p0];  int i0 = mgi[rb + 0 + p0];
          float v1 = mgv[rb + 8 + p1];  int i1 = mgi[rb + 8 + p1];
          float v2 = mgv[rb + 16 + p2]; int i2 = mgi[rb + 16 + p2];
          float v3 = mgv[rb + 24 + p3]; int i3 = mgi[rb + 24 + p3];
          float bv = v0; int bi = i0; int sel = 0;
          if (better(v1, i1, bv, bi)) { bv = v1; bi = i1; sel = 1; }
          if (better(v2, i2, bv, bi)) { bv = v2; bi = i2; sel = 2; }
          if (better(v3, i3, bv, bi)) { bv = v3; bi = i3; sel = 3; }
          cand_val[base + j] = bv;
          cand_idx[base + j] = bi;
          p0 += (sel == 0); p1 += (sel == 1); p2 += (sel == 2); p3 += (sel == 3);
        }
      }
      // reset running lists for next segment
#pragma unroll
      for (int n = 0; n < 2; ++n)
#pragma unroll
        for (int j = 0; j < TOPK; ++j) { lv[n][j] = -1e30f; li[n][j] = 0x7fffffff; }
    }
  }
}

// ---------------- K4: merge + exact fp32 rescore + select + gather ---------
__global__ __launch_bounds__(256) void merge_kernel(const float* __restrict__ qn,
                                                    const float* __restrict__ keys,
                                                    const float* __restrict__ values,
                                                    const float* __restrict__ rnk,
                                                    const float* __restrict__ cand_val,
                                                    const int* __restrict__ cand_idx,
                                                    float* __restrict__ out) {
  const int q = blockIdx.x;
  const int tid = threadIdx.x;
  const int lane = tid & 63;
  const int w = tid >> 6;
  __shared__ float sv[CANDS];
  __shared__ int si[CANDS];
  sv[tid] = cand_val[(size_t)q * CANDS + tid];
  si[tid] = cand_idx[(size_t)q * CANDS + tid];
  __syncthreads();
  for (int k = 2; k <= CANDS; k <<= 1) {
    for (int j = k >> 1; j > 0; j >>= 1) {
      int ixj = tid ^ j;
      if (ixj > tid) {
        float v0 = sv[tid], v1 = sv[ixj];
        int i0 = si[tid], i1 = si[ixj];
        bool desc = ((tid & k) == 0);
        bool dosw = desc ? better(v1, i1, v0, i0) : better(v0, i0, v1, i1);
        if (dosw) { sv[tid] = v1; si[tid] = i1; sv[ixj] = v0; si[ixj] = i0; }
      }
      __syncthreads();
    }
  }
  __shared__ float rsc[NRES];
  const float* qrow = &qn[(size_t)q * D_N + lane * 16];
  float4 qv0 = *reinterpret_cast<const float4*>(qrow + 0);
  float4 qv1 = *reinterpret_cast<const float4*>(qrow + 4);
  float4 qv2 = *reinterpret_cast<const float4*>(qrow + 8);
  float4 qv3 = *reinterpret_cast<const float4*>(qrow + 12);
  for (int c = w; c < NRES; c += 4) {
    int id = si[c];
    const float* kr = &keys[(size_t)id * D_N + lane * 16];
    float4 k0 = *reinterpret_cast<const float4*>(kr + 0);
    float4 k1 = *reinterpret_cast<const float4*>(kr + 4);
    float4 k2 = *reinterpret_cast<const float4*>(kr + 8);
    float4 k3 = *reinterpret_cast<const float4*>(kr + 12);
    float s = qv0.x * k0.x + qv0.y * k0.y + qv0.z * k0.z + qv0.w * k0.w
            + qv1.x * k1.x + qv1.y * k1.y + qv1.z * k1.z + qv1.w * k1.w
            + qv2.x * k2.x + qv2.y * k2.y + qv2.z * k2.z + qv2.w * k2.w
            + qv3.x * k3.x + qv3.y * k3.y + qv3.z * k3.z + qv3.w * k3.w;
#pragma unroll
    for (int off = 32; off > 0; off >>= 1) s += __shfl_down(s, off);
    if (lane == 0) rsc[c] = s * rnk[id];
  }
  __syncthreads();
  __shared__ int sel[TOPK];
  if (tid == 0) {
    unsigned used = 0;
    for (int j = 0; j < TOPK; ++j) {
      int best = -1;
      for (int c = 0; c < NRES; ++c) {
        if ((used >> c) & 1u) continue;
        if (best < 0 || better(rsc[c], si[c], rsc[best], si[best])) best = c;
      }
      used |= 1u << best;
      sel[j] = si[best];
    }
  }
  __syncthreads();
#pragma unroll
  for (int j = 0; j < TOPK; ++j) {
    int row = sel[j];
    float4 v = *reinterpret_cast<const float4*>(&values[(size_t)row * D_N + tid * 4]);
    *reinterpret_cast<float4*>(&out[(size_t)q * (TOPK * D_N) + j * D_N + tid * 4]) = v;
  }
}

extern "C" void kernel_launch(void* const* d_in, const int* in_sizes, int n_in,
                              void* d_out, int out_size, void* d_ws, size_t ws_size,
                              hipStream_t stream) {
  const float* query  = (const float*)d_in[0];
  const float* keys   = (const float*)d_in[1];
  const float* values = (const float*)d_in[2];
  float* out = (float*)d_out;
  char* ws = (char*)d_ws;

  const size_t offQn  = 0;
  const size_t offQb  = offQn + (size_t)Q_N * D_N * 4;
  const size_t offKb  = offQb + (size_t)Q_N * D_N * 2;
  const size_t offRnk = offKb + (size_t)M_N * D_N * 2;
  const size_t offCv  = offRnk + (size_t)M_N * 4;
  const size_t offCi  = offCv + (size_t)Q_N * CANDS * 4;

  float* qn = (float*)(ws + offQn);
  unsigned short* qb = (unsigned short*)(ws + offQb);
  unsigned short* kb = (unsigned short*)(ws + offKb);
  float* rnk = (float*)(ws + offRnk);
  float* cand_val = (float*)(ws + offCv);
  int* cand_idx = (int*)(ws + offCi);

  hipLaunchKernelGGL(knorm_scale_kernel, dim3(M_N), dim3(256), 0, stream, keys, kb, rnk);
  hipLaunchKernelGGL(qnorm_dual_kernel, dim3(Q_N), dim3(256), 0, stream, query, qn, qb);
  hipLaunchKernelGGL(simsb_kernel, dim3(256), dim3(256), 0, stream,
                     qb, kb, cand_val, cand_idx);
  hipLaunchKernelGGL(merge_kernel, dim3(Q_N), dim3(256), 0, stream,
                     qn, keys, values, rnk, cand_val, cand_idx, out);
}